// Round 3
// baseline (1350.103 us; speedup 1.0000x reference)
//
#include <hip/hip_runtime.h>

// Problem: B=64, C=256, H=W=56, HEADS=16, DH=16, WS=7, n1=n2=8, eps=1e-6
// Harness mode: inputs float32, OUTPUT float32 (threshold shows no bf16 floor;
// round-2 stub-identical error proved d_out is f32 and our u16 writes half-filled it).
// Strided windows: pixel h = ws_h*8 + win_h, w = ws_w*8 + win_w;
// window id = b*64 + win_h*8 + win_w; token id = ws_h*7 + ws_w.

typedef unsigned short u16;
typedef __attribute__((ext_vector_type(4))) float f32x4;
typedef __attribute__((ext_vector_type(8))) short short8;
typedef __attribute__((ext_vector_type(4))) short short4b;

__device__ __forceinline__ u16 f2bf(float f) {
  union { float f; unsigned int i; } v; v.f = f;
  unsigned int r = v.i + 0x7fffu + ((v.i >> 16) & 1u);   // RNE
  return (u16)(r >> 16);
}

// K1: eval-BN (f32) + transpose + window-gather -> A_ws[t'][c] bf16.
// One block per (b, win_h, ws_h): pixel row h = ws_h*8+win_h (56 px x 256 c).
__global__ __launch_bounds__(256) void k1_bn_gather(
    const float* __restrict__ x, const float* __restrict__ g,
    const float* __restrict__ be, const float* __restrict__ mu,
    const float* __restrict__ va, u16* __restrict__ aws)
{
  __shared__ u16 lds[56 * 264];   // [w][c], c padded 256->264
  const int tid = threadIdx.x;
  const int bx = blockIdx.x;
  const int ws_h = bx % 7, win_h = (bx / 7) % 8, b = bx / 56;
  const int h = ws_h * 8 + win_h;

  // load+BN: 256 c x 7 w-octets = 1792 tasks, 8 floats each
  for (int it = 0; it < 7; ++it) {
    int idx = it * 256 + tid;
    int c = idx / 7, oct = idx % 7;
    const float* src = x + (size_t)(b * 256 + c) * 3136 + h * 56 + oct * 8;
    float4 p0 = *(const float4*)src;
    float4 p1 = *(const float4*)(src + 4);
    float inv = g[c] * rsqrtf(va[c] + 1e-6f);
    float sh = be[c] - mu[c] * inv;
    float vals[8] = { p0.x, p0.y, p0.z, p0.w, p1.x, p1.y, p1.z, p1.w };
#pragma unroll
    for (int j = 0; j < 8; ++j)
      lds[(oct * 8 + j) * 264 + c] = f2bf(fmaf(vals[j], inv, sh));
  }
  __syncthreads();

  // write A_ws rows: 56 tokens x 32 c-octets (bf16, 16B stores)
  const size_t t0 = (size_t)(b * 64 + win_h * 8) * 49;
  for (int it = 0; it < 7; ++it) {
    int idx = it * 256 + tid;
    int tl = idx >> 5, coct = idx & 31;
    int win_w = tl / 7, ws_w = tl - win_w * 7;
    int w = ws_w * 8 + win_w;
    uint4 v = *(const uint4*)&lds[w * 264 + coct * 8];
    size_t tp = t0 + (size_t)win_w * 49 + ws_h * 7 + ws_w;
    *(uint4*)(aws + tp * 256 + coct * 8) = v;
  }
}

// K2: fused QKV projection + windowed attention + output assembly.
// One block (256 thr, 4 waves) per (b, win_h, head): 8 windows x 49 tokens.
__global__ __launch_bounds__(256, 2) void k2_attn(
    const u16* __restrict__ aws, const float* __restrict__ qkw,
    const float* __restrict__ vw, float* __restrict__ out)
{
  // LDS map (u16 units): sA [112][72] @0, sW [48][72] @8064,
  // sQK [8][49][36] @11520 (cols 0..15 q, 16..31 k; later per-window f32 O
  // [16][52] overlays each dead window region), sVT [8][16][52] @25632
  // (V transposed, cols 49..51 zeroed). Total 64576 B.
  __shared__ u16 smem[32288];
  u16* sA  = smem;
  u16* sW  = smem + 8064;
  u16* sQK = smem + 11520;
  u16* sVT = smem + 25632;

  const int tid = threadIdx.x;
  const int lane = tid & 63;
  const int wv = tid >> 6;
  const int l15 = lane & 15;
  const int quad = lane >> 4;
  const int kbase = quad * 4;
  const int bx = blockIdx.x;
  const int head = bx & 15;
  const int win_h = (bx >> 4) & 7;
  const int b = bx >> 7;
  const size_t t0 = (size_t)(b * 64 + win_h * 8) * 49;

  // zero VT pad columns 49..51 (read by clamped O-phase frags; must be finite)
  for (int i = tid; i < 8 * 16 * 3; i += 256) {
    int win = i / 48, r = (i % 48) / 3, pc = i % 3;
    sVT[win * 832 + r * 52 + 49 + pc] = 0;
  }

  // ---- projection: 4 quarters of 2 windows (M=98 pad 112, N=48, K=256) ----
  const int mt0 = wv * 2;                  // wave m-tile range (7 tiles: 2,2,2,1)
  const int nmt = (wv == 3) ? 1 : 2;

  for (int qi = 0; qi < 4; ++qi) {
    f32x4 acc[2][3];
    for (int i = 0; i < 2; ++i)
      for (int j = 0; j < 3; ++j) acc[i][j] = (f32x4)(0.0f);

    for (int kb = 0; kb < 4; ++kb) {       // BK = 64
      __syncthreads();
      // stage A tile: 98 rows x 8 octets (rows contiguous in A_ws, bf16)
      for (int it = 0; it < 4; ++it) {
        int idx = it * 256 + tid;
        if (idx < 784) {
          int r = idx >> 3, oct = idx & 7;
          const u16* src = aws + (t0 + qi * 98 + r) * 256 + kb * 64 + oct * 8;
          *(uint4*)&sA[r * 72 + oct * 8] = *(const uint4*)src;
        }
      }
      // stage W tile (f32 -> bf16): rows 0..15 q, 16..31 k, 32..47 v
      for (int idx = tid; idx < 384; idx += 256) {
        int n = idx >> 3, oct = idx & 7;
        const float* src;
        if (n < 16)      src = qkw + (size_t)(head * 16 + n) * 256;
        else if (n < 32) src = qkw + (size_t)(256 + head * 16 + (n - 16)) * 256;
        else             src = vw  + (size_t)(head * 16 + (n - 32)) * 256;
        src += kb * 64 + oct * 8;
        float4 a = *(const float4*)src;
        float4 c = *(const float4*)(src + 4);
        uint4 pk;
        pk.x = (unsigned)f2bf(a.x) | ((unsigned)f2bf(a.y) << 16);
        pk.y = (unsigned)f2bf(a.z) | ((unsigned)f2bf(a.w) << 16);
        pk.z = (unsigned)f2bf(c.x) | ((unsigned)f2bf(c.y) << 16);
        pk.w = (unsigned)f2bf(c.z) | ((unsigned)f2bf(c.w) << 16);
        *(uint4*)&sW[n * 72 + oct * 8] = pk;
      }
      __syncthreads();
#pragma unroll
      for (int ks = 0; ks < 2; ++ks) {     // two K=32 steps
        int col = ks * 32 + quad * 8;
        short8 wfrag[3];
#pragma unroll
        for (int nt = 0; nt < 3; ++nt)
          wfrag[nt] = *(const short8*)&sW[(nt * 16 + l15) * 72 + col];
        for (int im = 0; im < nmt; ++im) {
          short8 af = *(const short8*)&sA[((mt0 + im) * 16 + l15) * 72 + col];
#pragma unroll
          for (int nt = 0; nt < 3; ++nt)
            acc[im][nt] = __builtin_amdgcn_mfma_f32_16x16x32_bf16(
                af, wfrag[nt], acc[im][nt], 0, 0, 0);
        }
      }
    }
    // scatter acc -> q/k rows and transposed V (relu)
    for (int im = 0; im < nmt; ++im) {
#pragma unroll
      for (int r = 0; r < 4; ++r) {
        int lt = (mt0 + im) * 16 + kbase + r;   // token row in quarter
        if (lt < 98) {
          int wl = lt / 49;
          int tok = lt - wl * 49;
          int win = qi * 2 + wl;
          u16* qkrow = sQK + win * 1764 + tok * 36;
          u16* vtw = sVT + win * 832;
#pragma unroll
          for (int nt = 0; nt < 3; ++nt) {
            int n = nt * 16 + l15;
            float v = acc[im][nt][r];
            if (n < 32) qkrow[n] = f2bf(v);
            else        vtw[(n - 32) * 52 + tok] = f2bf(fmaxf(v, 0.0f));
          }
        }
      }
    }
  }
  __syncthreads();

  // ---- attention: wave handles 2 windows; S^T trick keeps P in registers ----
  const float SM = 0.36067376022224085f;   // dh^-0.5 * log2(e)
  for (int rep = 0; rep < 2; ++rep) {
    int win = wv * 2 + rep;
    const u16* qk = sQK + win * 1764;
    const u16* vt = sVT + win * 832;

    short4b ka[4], qb[4];
#pragma unroll
    for (int t = 0; t < 4; ++t) {
      int rk = t * 16 + l15; rk = (rk > 48) ? 48 : rk;   // clamp: finite data
      ka[t] = *(const short4b*)&qk[rk * 36 + 16 + kbase]; // K[tok][d]
      qb[t] = *(const short4b*)&qk[rk * 36 + kbase];      // Q[tok][d]
    }
    f32x4 zz = (f32x4)(0.0f);
    f32x4 s[4][4];                      // S^T tiles: [mt over ktok][nt over q]
#pragma unroll
    for (int mt = 0; mt < 4; ++mt)
#pragma unroll
      for (int nt = 0; nt < 4; ++nt)
        s[mt][nt] = __builtin_amdgcn_mfma_f32_16x16x16bf16_1k(
            ka[mt], qb[nt], zz, 0, 0, 0);

    float inv_sum[4];
    short4b pf[4][4];                   // P^T frags == B-operand layout
#pragma unroll
    for (int nt = 0; nt < 4; ++nt) {
      float m = -1e30f;
#pragma unroll
      for (int mt = 0; mt < 4; ++mt)
#pragma unroll
        for (int r = 0; r < 4; ++r) {
          int kt = mt * 16 + kbase + r;
          float v = (kt < 49) ? s[mt][nt][r] : -1e30f;
          m = fmaxf(m, v);
        }
      m = fmaxf(m, __shfl_xor(m, 16, 64));
      m = fmaxf(m, __shfl_xor(m, 32, 64));
      float sum = 0.0f;
#pragma unroll
      for (int mt = 0; mt < 4; ++mt)
#pragma unroll
        for (int r = 0; r < 4; ++r) {
          int kt = mt * 16 + kbase + r;
          float p = (kt < 49) ? exp2f((s[mt][nt][r] - m) * SM) : 0.0f;
          sum += p;
          pf[mt][nt][r] = (short)f2bf(p);
        }
      sum += __shfl_xor(sum, 16, 64);
      sum += __shfl_xor(sum, 32, 64);
      inv_sum[nt] = 1.0f / sum;        // defer normalize to epilogue
    }

    f32x4 o[4];
#pragma unroll
    for (int nt = 0; nt < 4; ++nt) o[nt] = zz;
#pragma unroll
    for (int kt = 0; kt < 4; ++kt) {
      int ct = kt * 16 + kbase; ct = (ct > 48) ? 48 : ct;  // clamp; pf=0 masks
      short4b vfrag = *(const short4b*)&vt[l15 * 52 + ct]; // V^T[d][tok]
#pragma unroll
      for (int nt = 0; nt < 4; ++nt)
        o[nt] = __builtin_amdgcn_mfma_f32_16x16x16bf16_1k(
            vfrag, pf[kt][nt], o[nt], 0, 0, 0);
    }

    // O^T: lane holds q = nt*16+l15 (col), d = kbase+r (row).
    // Store f32 O[d][q] (pitch 52) into this window's now-dead sQK region
    // (3328 B <= 3528 B; only this wave ever touches window `win`).
    float* sO = (float*)(sQK + win * 1764);
#pragma unroll
    for (int nt = 0; nt < 4; ++nt) {
      int q = nt * 16 + l15;
      if (q < 49) {
#pragma unroll
        for (int r = 0; r < 4; ++r)
          sO[(kbase + r) * 52 + q] = o[nt][r] * inv_sum[nt];
      }
    }
  }
  __syncthreads();

  // coalesced f32 store: rows out[b][head*16+d][wsh*8+win_h][0..55]
  // pixel w = wsw*8 + win_w -> window region (w&7), token col (w>>3)
  {
    size_t obase = (size_t)(b * 256 + head * 16) * 3136;
    for (int i = tid; i < 3136; i += 256) {     // float2 tasks
      int d = i / 196, rem = i - d * 196;
      int wsh = rem / 28, dwp = rem - wsh * 28;
      int w0 = dwp * 2, w1 = w0 + 1;
      const float* sO0 = (const float*)(sQK + (w0 & 7) * 1764);
      const float* sO1 = (const float*)(sQK + (w1 & 7) * 1764);
      float2 val;
      val.x = sO0[d * 52 + wsh * 7 + (w0 >> 3)];
      val.y = sO1[d * 52 + wsh * 7 + (w1 >> 3)];
      *(float2*)(out + obase + (size_t)d * 3136 +
                 (wsh * 8 + win_h) * 56 + w0) = val;
    }
  }
}

extern "C" void kernel_launch(void* const* d_in, const int* in_sizes, int n_in,
                              void* d_out, int out_size, void* d_ws, size_t ws_size,
                              hipStream_t stream) {
  const float* x   = (const float*)d_in[0];
  const float* g   = (const float*)d_in[1];
  const float* be  = (const float*)d_in[2];
  const float* mu  = (const float*)d_in[3];
  const float* va  = (const float*)d_in[4];
  const float* qkw = (const float*)d_in[5];
  const float* vw  = (const float*)d_in[6];
  u16* aws = (u16*)d_ws;                 // 200704 x 256 bf16 = 98 MB token matrix
  float* outp = (float*)d_out;

  k1_bn_gather<<<64 * 8 * 7, 256, 0, stream>>>(x, g, be, mu, va, aws);
  k2_attn<<<64 * 8 * 16, 256, 0, stream>>>(aws, qkw, vw, outp);
}